// Round 6
// baseline (149.305 us; speedup 1.0000x reference)
//
#include <hip/hip_runtime.h>
#include <math.h>

namespace {
constexpr int B_ = 16;
constexpr int L_ = 1534;
constexpr int LC = L_ * 16;        // 24544 floats per batch row
constexpr int O1 = 1023;           // L - 512 + 1
constexpr int K_ = 8192;           // SIZE * C
constexpr int KSPLIT = 16;
constexpr int KQ = K_ / KSPLIT;    // 512
constexpr int KC = 256;            // chunk (floats of K per inner stage)
constexpr int OUTL = 1535;         // L + 1
constexpr float EPS = 1e-3f;
constexpr int XS_F4 = 112;         // x LDS row: 448 floats
constexpr int WS_F4 = 80;          // W LDS row: 320 floats (48 halo + 256 + pad)
constexpr int W_SLOTS = 16 * WS_F4;  // 1280
constexpr int X_SLOTS = 16 * XS_F4;  // 1792
constexpr int H1P_FLOATS = KSPLIT * B_ * O1;  // 261888
}

// ---------------- Stage 1: h1 k-split partials ----------------
// h1[b,o] = sum_q x[b, o*16+q] * W1[o, q].
// Block (tile, split): o in [tile*16,+16), q in [split*512,+512), 2 chunks
// of 256 (split 15 runs a 3rd hole-filler chunk at qc=8192: per-o coverage
// [qc-16jj, qc+256-16jj) misses [8192-16jj, 8192), covered there with W
// zero-guarded beyond K).
// R6: KSPLIT=16 + launch_bounds(512,6) [3 blocks/CU target, VGPR cap ~85]
// with the PROVEN R4 staging (two tmp[3] rounds, ~12 staging VGPRs — R5's
// tmp[6] overflowed the cap and spilled acc: VGPR 40, WRITE_SIZE 44 MB).
__global__ __launch_bounds__(512, 6) void k_h1(const float* __restrict__ x,
                                               const float* __restrict__ W1,
                                               float* __restrict__ h1p,
                                               float* __restrict__ gacc) {
  __shared__ float4 xs[X_SLOTS];    // 28 KB
  __shared__ float4 wsld[W_SLOTS];  // 20 KB

  const int tile = (int)blockIdx.x >> 4;  // 0..63
  const int split = (int)blockIdx.x & 15; // 0..15
  const int o0 = tile * 16;
  const int q0 = split * KQ;
  const int t = (int)threadIdx.x;
  const int bgrp = t >> 8;        // 0..1
  const int ogrp = (t >> 6) & 3;  // 0..3
  const int ks = t & 63;          // 0..63

  const float4 z4 = make_float4(0.f, 0.f, 0.f, 0.f);

  float acc[4][8];
#pragma unroll
  for (int j = 0; j < 4; ++j)
#pragma unroll
    for (int i = 0; i < 8; ++i) acc[j][i] = 0.f;

  const int nc = (split == KSPLIT - 1) ? 3 : 2;  // split 15 covers the K hole
  for (int c = 0; c < nc; ++c) {
    const int qc = q0 + c * KC;  // absolute W-column base of this chunk
    if (c > 0) __syncthreads();  // previous chunk's LDS reads complete

    // ---- stage chunk c: slots [0,1280) = W, [1280,3072) = x.
    // Two rounds of 3: loads batched before stores (>=3 in flight), low
    // register footprint (12 VGPRs).
#pragma unroll
    for (int rnd = 0; rnd < 2; ++rnd) {
      float4 tmp[3];
#pragma unroll
      for (int k = 0; k < 3; ++k) {
        const int idx = t + (rnd * 3 + k) * 512;  // 0..3071
        float4 v = z4;
        if (idx < W_SLOTS) {
          const int ol = idx / WS_F4;
          const int f4 = idx - ol * WS_F4;
          const int q = qc - 48 + 4 * f4;
          const int o = o0 + ol;
          if (o < O1 && q >= 0 && q <= K_ - 4)
            v = *(const float4*)(W1 + o * K_ + q);
        } else {
          const int xi = idx - W_SLOTS;
          const int row = xi / XS_F4;
          const int f4 = xi - row * XS_F4;
          const int p = o0 * 16 + qc + 4 * f4;
          if (p <= LC - 4) v = *(const float4*)(x + row * LC + p);
        }
        tmp[k] = v;
      }
#pragma unroll
      for (int k = 0; k < 3; ++k) {
        const int idx = t + (rnd * 3 + k) * 512;
        if (idx < W_SLOTS) wsld[idx] = tmp[k];
        else xs[idx - W_SLOTS] = tmp[k];
      }
    }
    __syncthreads();

    // ---- compute chunk c from LDS (consecutive-lane b128 reads, no conflict)
    float4 wvv[4];
#pragma unroll
    for (int jj = 0; jj < 4; ++jj)
      wvv[jj] = wsld[(ogrp * 4 + jj) * WS_F4 + (ks - 4 * jj + 12)];
    float4 xv[8];
#pragma unroll
    for (int bi = 0; bi < 8; ++bi)
      xv[bi] = xs[(bgrp * 8 + bi) * XS_F4 + (ogrp * 16 + ks)];
#pragma unroll
    for (int jj = 0; jj < 4; ++jj)
#pragma unroll
      for (int bi = 0; bi < 8; ++bi) {
        acc[jj][bi] = fmaf(xv[bi].x, wvv[jj].x, acc[jj][bi]);
        acc[jj][bi] = fmaf(xv[bi].y, wvv[jj].y, acc[jj][bi]);
        acc[jj][bi] = fmaf(xv[bi].z, wvv[jj].z, acc[jj][bi]);
        acc[jj][bi] = fmaf(xv[bi].w, wvv[jj].w, acc[jj][bi]);
      }
  }

  // ---- reduce over ks (64 partials per output), 4 rounds, stride-9 pad.
  // write banks: (9*lane + i) % 32 -> 2-way (free); read banks:
  // (8*seg + bi) % 32 -> 2-way (free).
  float* redf = (float*)xs;  // 512*9 = 4608 floats <= 7168 available
  const int cls = bgrp * 4 + ogrp;  // == wave id 0..7
#pragma unroll
  for (int r = 0; r < 4; ++r) {
    __syncthreads();
#pragma unroll
    for (int i = 0; i < 8; ++i) redf[(cls * 64 + ks) * 9 + i] = acc[r][i];
    __syncthreads();
    const int out = t >> 3;  // 0..63
    const int seg = t & 7;
    const int rcls = out >> 3, bi = out & 7;
    float v = 0.f;
#pragma unroll
    for (int j = 0; j < 8; ++j)
      v += redf[(rcls * 64 + seg * 8 + j) * 9 + bi];
    v += __shfl_xor(v, 1, 64);
    v += __shfl_xor(v, 2, 64);
    v += __shfl_xor(v, 4, 64);
    if (seg == 0) {
      const int b = (rcls >> 2) * 8 + bi;
      const int o = o0 + (rcls & 3) * 4 + r;
      if (o < O1) h1p[(split * B_ + b) * O1 + o] = v;
    }
  }
  // zero lin/sig accumulators for stage 2 (stream order guarantees visibility)
  if (blockIdx.x == 0 && t < 32) gacc[t] = 0.f;
}

// ---------------- Stage 2: h2 -> partial lin/sig ----------------
__global__ __launch_bounds__(256) void k_h2(const float* __restrict__ h1p,
                                            const float* __restrict__ b1,
                                            const float* __restrict__ W2,
                                            const float* __restrict__ b2,
                                            const float* __restrict__ Wl,
                                            const float* __restrict__ Wsg,
                                            float* __restrict__ gacc) {
  const int bid = (int)blockIdx.x;
  const int b = bid >> 3;
  const int tile = bid & 7;
  const int base = tile * 64;
  const int t = (int)threadIdx.x;
  const int wave = t >> 6;
  const int lane = t & 63;

  __shared__ float hw[575];  // ELU(h1) window [base, base+575)
  for (int i = t; i < 575; i += 256) {
    const int o = base + i;
    float v = b1[o];
#pragma unroll
    for (int s = 0; s < KSPLIT; ++s) v += h1p[(s * B_ + b) * O1 + o];
    hw[i] = v > 0.f ? v : expm1f(v);  // ELU alpha=1
  }
  __syncthreads();

  float lin_acc = 0.f, sig_acc = 0.f;
  for (int i = wave; i < 64; i += 4) {
    const int o2 = base + i;
    const float4 wa = *(const float4*)(W2 + o2 * 512 + lane * 4);
    const float4 wb = *(const float4*)(W2 + o2 * 512 + 256 + lane * 4);
    const int sa = i + lane * 4;
    float a = 0.f;
    a = fmaf(hw[sa + 0], wa.x, a);
    a = fmaf(hw[sa + 1], wa.y, a);
    a = fmaf(hw[sa + 2], wa.z, a);
    a = fmaf(hw[sa + 3], wa.w, a);
    a = fmaf(hw[sa + 256], wb.x, a);
    a = fmaf(hw[sa + 257], wb.y, a);
    a = fmaf(hw[sa + 258], wb.z, a);
    a = fmaf(hw[sa + 259], wb.w, a);
#pragma unroll
    for (int off = 32; off >= 1; off >>= 1) a += __shfl_xor(a, off, 64);
    const float h2 = a + b2[o2];
    lin_acc = fmaf(h2, Wl[o2], lin_acc);
    sig_acc = fmaf(h2, Wsg[o2], sig_acc);
  }

  __shared__ float lred[4], sred[4];
  if (lane == 0) { lred[wave] = lin_acc; sred[wave] = sig_acc; }
  __syncthreads();
  if (t == 0) {
    atomicAdd(&gacc[b], lred[0] + lred[1] + lred[2] + lred[3]);
    atomicAdd(&gacc[16 + b], sred[0] + sred[1] + sred[2] + sred[3]);
  }
}

// ---------------- Stage 3: residual + batchnorm epilogue ----------------
__global__ __launch_bounds__(256) void k_out(const float* __restrict__ x,
                                             const float* __restrict__ gacc,
                                             const float* __restrict__ bl,
                                             const float* __restrict__ bs,
                                             const float* __restrict__ gamma,
                                             const float* __restrict__ beta,
                                             const float* __restrict__ mmean,
                                             const float* __restrict__ mvar,
                                             float* __restrict__ out) {
  const int f4 = blockIdx.x * 256 + (int)threadIdx.x;
  if (f4 >= B_ * OUTL * 4) return;
  const int b = f4 / (OUTL * 4);
  const int q = f4 - b * (OUTL * 4);
  const int l = q >> 2;
  const int c0 = (q & 3) * 4;

  const float lin = gacc[b] + bl[0];
  const float sv = gacc[16 + b] + bs[0];
  const float g = lin * (1.f / (1.f + expf(-sv)));

  float4 xin = make_float4(0.f, 0.f, 0.f, 0.f);
  if (l < L_) xin = *(const float4*)(x + b * LC + l * 16 + c0);

  const float4 gm = *(const float4*)(gamma + c0);
  const float4 bt = *(const float4*)(beta + c0);
  const float4 mm = *(const float4*)(mmean + c0);
  const float4 mv = *(const float4*)(mvar + c0);

  float4 r;
  r.x = (xin.x + g - mm.x) * (rsqrtf(mv.x + EPS) * gm.x) + bt.x;
  r.y = (xin.y + g - mm.y) * (rsqrtf(mv.y + EPS) * gm.y) + bt.y;
  r.z = (xin.z + g - mm.z) * (rsqrtf(mv.z + EPS) * gm.z) + bt.z;
  r.w = (xin.w + g - mm.w) * (rsqrtf(mv.w + EPS) * gm.w) + bt.w;
  *(float4*)(out + f4 * 4) = r;
}

extern "C" void kernel_launch(void* const* d_in, const int* in_sizes, int n_in,
                              void* d_out, int out_size, void* d_ws, size_t ws_size,
                              hipStream_t stream) {
  const float* x    = (const float*)d_in[0];
  const float* W1   = (const float*)d_in[1];
  const float* b1   = (const float*)d_in[2];
  const float* W2   = (const float*)d_in[3];
  const float* b2   = (const float*)d_in[4];
  const float* Wl   = (const float*)d_in[5];
  const float* bl   = (const float*)d_in[6];
  const float* Wsg  = (const float*)d_in[7];
  const float* bs   = (const float*)d_in[8];
  const float* gm   = (const float*)d_in[9];
  const float* bt   = (const float*)d_in[10];
  const float* mmn  = (const float*)d_in[11];
  const float* mvr  = (const float*)d_in[12];

  float* ws   = (float*)d_ws;
  float* h1p  = ws;                // [16][16][1023] k-split partials
  float* gacc = ws + H1P_FLOATS;   // lin[16], sig[16]

  k_h1<<<64 * KSPLIT, 512, 0, stream>>>(x, W1, h1p, gacc);
  k_h2<<<128, 256, 0, stream>>>(h1p, b1, W2, b2, Wl, Wsg, gacc);
  k_out<<<(B_ * OUTL * 4 + 255) / 256, 256, 0, stream>>>(
      x, gacc, bl, bs, gm, bt, mmn, mvr, (float*)d_out);
}

// Round 7
// 127.459 us; speedup vs baseline: 1.1714x; 1.1714x over previous
//
#include <hip/hip_runtime.h>
#include <math.h>

namespace {
constexpr int B_ = 16;
constexpr int L_ = 1534;
constexpr int LC = L_ * 16;        // 24544 floats per batch row
constexpr int O1 = 1023;           // L - 512 + 1
constexpr int K_ = 8192;           // SIZE * C
constexpr int KSPLIT = 16;
constexpr int KQ = K_ / KSPLIT;    // 512
constexpr int KC = 256;            // chunk (floats of K per inner stage)
constexpr int OUTL = 1535;         // L + 1
constexpr float EPS = 1e-3f;
constexpr int XS_F4 = 112;         // x LDS row: 448 floats
constexpr int WS_F4 = 80;          // W LDS row: 320 floats (48 halo + 256 + pad)
constexpr int W_SLOTS = 16 * WS_F4;  // 1280
constexpr int X_SLOTS = 16 * XS_F4;  // 1792
constexpr int H1P_FLOATS = KSPLIT * B_ * O1;  // 261888
}

// ---------------- Stage 1: h1 k-split partials ----------------
// h1[b,o] = sum_q x[b, o*16+q] * W1[o, q].
// Block (tile, split): o in [tile*16,+16), q in [split*512,+512), 2 chunks
// of 256 (split 15 runs a 3rd hole-filler chunk at qc=8192: per-o coverage
// [qc-16jj, qc+256-16jj) misses [8192-16jj, 8192), covered there with W
// zero-guarded beyond K).
// R7: KSPLIT=16 (grid 1024 -> 3 resident blocks/CU; R4's occupancy was
// grid-capped at 2) with R4's PROVEN launch_bounds(512,4) [VGPR cap 128 ->
// compiler picks ~64, no spill]. R5/R6's (512,6) capped VGPR at ~84 < the
// ~90 live set -> allocator collapse + scratch spill (VGPR 40, WRITE 44 MB).
__global__ __launch_bounds__(512, 4) void k_h1(const float* __restrict__ x,
                                               const float* __restrict__ W1,
                                               float* __restrict__ h1p,
                                               float* __restrict__ gacc) {
  __shared__ float4 xs[X_SLOTS];    // 28 KB
  __shared__ float4 wsld[W_SLOTS];  // 20 KB

  const int tile = (int)blockIdx.x >> 4;  // 0..63
  const int split = (int)blockIdx.x & 15; // 0..15
  const int o0 = tile * 16;
  const int q0 = split * KQ;
  const int t = (int)threadIdx.x;
  const int bgrp = t >> 8;        // 0..1
  const int ogrp = (t >> 6) & 3;  // 0..3
  const int ks = t & 63;          // 0..63

  const float4 z4 = make_float4(0.f, 0.f, 0.f, 0.f);

  float acc[4][8];
#pragma unroll
  for (int j = 0; j < 4; ++j)
#pragma unroll
    for (int i = 0; i < 8; ++i) acc[j][i] = 0.f;

  const int nc = (split == KSPLIT - 1) ? 3 : 2;  // split 15 covers the K hole
  for (int c = 0; c < nc; ++c) {
    const int qc = q0 + c * KC;  // absolute W-column base of this chunk
    if (c > 0) __syncthreads();  // previous chunk's LDS reads complete

    // ---- stage chunk c: slots [0,1280) = W, [1280,3072) = x.
    // Two rounds of 3: loads batched before stores (>=3 in flight), low
    // register footprint (12 VGPRs).
#pragma unroll
    for (int rnd = 0; rnd < 2; ++rnd) {
      float4 tmp[3];
#pragma unroll
      for (int k = 0; k < 3; ++k) {
        const int idx = t + (rnd * 3 + k) * 512;  // 0..3071
        float4 v = z4;
        if (idx < W_SLOTS) {
          const int ol = idx / WS_F4;
          const int f4 = idx - ol * WS_F4;
          const int q = qc - 48 + 4 * f4;
          const int o = o0 + ol;
          if (o < O1 && q >= 0 && q <= K_ - 4)
            v = *(const float4*)(W1 + o * K_ + q);
        } else {
          const int xi = idx - W_SLOTS;
          const int row = xi / XS_F4;
          const int f4 = xi - row * XS_F4;
          const int p = o0 * 16 + qc + 4 * f4;
          if (p <= LC - 4) v = *(const float4*)(x + row * LC + p);
        }
        tmp[k] = v;
      }
#pragma unroll
      for (int k = 0; k < 3; ++k) {
        const int idx = t + (rnd * 3 + k) * 512;
        if (idx < W_SLOTS) wsld[idx] = tmp[k];
        else xs[idx - W_SLOTS] = tmp[k];
      }
    }
    __syncthreads();

    // ---- compute chunk c from LDS (consecutive-lane b128 reads, no conflict)
    float4 wvv[4];
#pragma unroll
    for (int jj = 0; jj < 4; ++jj)
      wvv[jj] = wsld[(ogrp * 4 + jj) * WS_F4 + (ks - 4 * jj + 12)];
    float4 xv[8];
#pragma unroll
    for (int bi = 0; bi < 8; ++bi)
      xv[bi] = xs[(bgrp * 8 + bi) * XS_F4 + (ogrp * 16 + ks)];
#pragma unroll
    for (int jj = 0; jj < 4; ++jj)
#pragma unroll
      for (int bi = 0; bi < 8; ++bi) {
        acc[jj][bi] = fmaf(xv[bi].x, wvv[jj].x, acc[jj][bi]);
        acc[jj][bi] = fmaf(xv[bi].y, wvv[jj].y, acc[jj][bi]);
        acc[jj][bi] = fmaf(xv[bi].z, wvv[jj].z, acc[jj][bi]);
        acc[jj][bi] = fmaf(xv[bi].w, wvv[jj].w, acc[jj][bi]);
      }
  }

  // ---- reduce over ks (64 partials per output), 4 rounds, stride-9 pad.
  // write banks: (9*lane + i) % 32 -> 2-way (free); read banks:
  // (8*seg + bi) % 32 -> 2-way (free).
  float* redf = (float*)xs;  // 512*9 = 4608 floats <= 7168 available
  const int cls = bgrp * 4 + ogrp;  // == wave id 0..7
#pragma unroll
  for (int r = 0; r < 4; ++r) {
    __syncthreads();
#pragma unroll
    for (int i = 0; i < 8; ++i) redf[(cls * 64 + ks) * 9 + i] = acc[r][i];
    __syncthreads();
    const int out = t >> 3;  // 0..63
    const int seg = t & 7;
    const int rcls = out >> 3, bi = out & 7;
    float v = 0.f;
#pragma unroll
    for (int j = 0; j < 8; ++j)
      v += redf[(rcls * 64 + seg * 8 + j) * 9 + bi];
    v += __shfl_xor(v, 1, 64);
    v += __shfl_xor(v, 2, 64);
    v += __shfl_xor(v, 4, 64);
    if (seg == 0) {
      const int b = (rcls >> 2) * 8 + bi;
      const int o = o0 + (rcls & 3) * 4 + r;
      if (o < O1) h1p[(split * B_ + b) * O1 + o] = v;
    }
  }
  // zero lin/sig accumulators for stage 2 (stream order guarantees visibility)
  if (blockIdx.x == 0 && t < 32) gacc[t] = 0.f;
}

// ---------------- Stage 2: h2 -> partial lin/sig ----------------
__global__ __launch_bounds__(256) void k_h2(const float* __restrict__ h1p,
                                            const float* __restrict__ b1,
                                            const float* __restrict__ W2,
                                            const float* __restrict__ b2,
                                            const float* __restrict__ Wl,
                                            const float* __restrict__ Wsg,
                                            float* __restrict__ gacc) {
  const int bid = (int)blockIdx.x;
  const int b = bid >> 3;
  const int tile = bid & 7;
  const int base = tile * 64;
  const int t = (int)threadIdx.x;
  const int wave = t >> 6;
  const int lane = t & 63;

  __shared__ float hw[575];  // ELU(h1) window [base, base+575)
  for (int i = t; i < 575; i += 256) {
    const int o = base + i;
    float v = b1[o];
#pragma unroll
    for (int s = 0; s < KSPLIT; ++s) v += h1p[(s * B_ + b) * O1 + o];
    hw[i] = v > 0.f ? v : expm1f(v);  // ELU alpha=1
  }
  __syncthreads();

  float lin_acc = 0.f, sig_acc = 0.f;
  for (int i = wave; i < 64; i += 4) {
    const int o2 = base + i;
    const float4 wa = *(const float4*)(W2 + o2 * 512 + lane * 4);
    const float4 wb = *(const float4*)(W2 + o2 * 512 + 256 + lane * 4);
    const int sa = i + lane * 4;
    float a = 0.f;
    a = fmaf(hw[sa + 0], wa.x, a);
    a = fmaf(hw[sa + 1], wa.y, a);
    a = fmaf(hw[sa + 2], wa.z, a);
    a = fmaf(hw[sa + 3], wa.w, a);
    a = fmaf(hw[sa + 256], wb.x, a);
    a = fmaf(hw[sa + 257], wb.y, a);
    a = fmaf(hw[sa + 258], wb.z, a);
    a = fmaf(hw[sa + 259], wb.w, a);
#pragma unroll
    for (int off = 32; off >= 1; off >>= 1) a += __shfl_xor(a, off, 64);
    const float h2 = a + b2[o2];
    lin_acc = fmaf(h2, Wl[o2], lin_acc);
    sig_acc = fmaf(h2, Wsg[o2], sig_acc);
  }

  __shared__ float lred[4], sred[4];
  if (lane == 0) { lred[wave] = lin_acc; sred[wave] = sig_acc; }
  __syncthreads();
  if (t == 0) {
    atomicAdd(&gacc[b], lred[0] + lred[1] + lred[2] + lred[3]);
    atomicAdd(&gacc[16 + b], sred[0] + sred[1] + sred[2] + sred[3]);
  }
}

// ---------------- Stage 3: residual + batchnorm epilogue ----------------
__global__ __launch_bounds__(256) void k_out(const float* __restrict__ x,
                                             const float* __restrict__ gacc,
                                             const float* __restrict__ bl,
                                             const float* __restrict__ bs,
                                             const float* __restrict__ gamma,
                                             const float* __restrict__ beta,
                                             const float* __restrict__ mmean,
                                             const float* __restrict__ mvar,
                                             float* __restrict__ out) {
  const int f4 = blockIdx.x * 256 + (int)threadIdx.x;
  if (f4 >= B_ * OUTL * 4) return;
  const int b = f4 / (OUTL * 4);
  const int q = f4 - b * (OUTL * 4);
  const int l = q >> 2;
  const int c0 = (q & 3) * 4;

  const float lin = gacc[b] + bl[0];
  const float sv = gacc[16 + b] + bs[0];
  const float g = lin * (1.f / (1.f + expf(-sv)));

  float4 xin = make_float4(0.f, 0.f, 0.f, 0.f);
  if (l < L_) xin = *(const float4*)(x + b * LC + l * 16 + c0);

  const float4 gm = *(const float4*)(gamma + c0);
  const float4 bt = *(const float4*)(beta + c0);
  const float4 mm = *(const float4*)(mmean + c0);
  const float4 mv = *(const float4*)(mvar + c0);

  float4 r;
  r.x = (xin.x + g - mm.x) * (rsqrtf(mv.x + EPS) * gm.x) + bt.x;
  r.y = (xin.y + g - mm.y) * (rsqrtf(mv.y + EPS) * gm.y) + bt.y;
  r.z = (xin.z + g - mm.z) * (rsqrtf(mv.z + EPS) * gm.z) + bt.z;
  r.w = (xin.w + g - mm.w) * (rsqrtf(mv.w + EPS) * gm.w) + bt.w;
  *(float4*)(out + f4 * 4) = r;
}

extern "C" void kernel_launch(void* const* d_in, const int* in_sizes, int n_in,
                              void* d_out, int out_size, void* d_ws, size_t ws_size,
                              hipStream_t stream) {
  const float* x    = (const float*)d_in[0];
  const float* W1   = (const float*)d_in[1];
  const float* b1   = (const float*)d_in[2];
  const float* W2   = (const float*)d_in[3];
  const float* b2   = (const float*)d_in[4];
  const float* Wl   = (const float*)d_in[5];
  const float* bl   = (const float*)d_in[6];
  const float* Wsg  = (const float*)d_in[7];
  const float* bs   = (const float*)d_in[8];
  const float* gm   = (const float*)d_in[9];
  const float* bt   = (const float*)d_in[10];
  const float* mmn  = (const float*)d_in[11];
  const float* mvr  = (const float*)d_in[12];

  float* ws   = (float*)d_ws;
  float* h1p  = ws;                // [16][16][1023] k-split partials
  float* gacc = ws + H1P_FLOATS;   // lin[16], sig[16]

  k_h1<<<64 * KSPLIT, 512, 0, stream>>>(x, W1, h1p, gacc);
  k_h2<<<128, 256, 0, stream>>>(h1p, b1, W2, b2, Wl, Wsg, gacc);
  k_out<<<(B_ * OUTL * 4 + 255) / 256, 256, 0, stream>>>(
      x, gacc, bl, bs, gm, bt, mmn, mvr, (float*)d_out);
}

// Round 8
// 120.596 us; speedup vs baseline: 1.2381x; 1.0569x over previous
//
#include <hip/hip_runtime.h>
#include <math.h>

namespace {
constexpr int B_ = 16;
constexpr int L_ = 1534;
constexpr int LC = L_ * 16;        // 24544 floats per batch row
constexpr int O1 = 1023;           // L - 512 + 1
constexpr int K_ = 8192;           // SIZE * C
constexpr int KSPLIT = 8;
constexpr int KQ = K_ / KSPLIT;    // 1024
constexpr int KC = 256;            // chunk (floats of K per inner stage)
constexpr int OUTL = 1535;         // L + 1
constexpr float EPS = 1e-3f;
constexpr int H1P_FLOATS = KSPLIT * B_ * O1;  // 130944
}

// ---------------- Stage 1: h1 k-split partials ----------------
// h1[b,o] = sum_q x[b, o*16+q] * W1[o, q].
// Block (tile, split): o in [tile*16,+16), q in [split*1024,+1024), 4 chunks
// of 256 (split 7 runs a 5th hole-filler chunk at qc=8192: per-o coverage
// [qc-16jj, qc+256-16jj) misses [8192-16jj, 8192), covered there with W
// zero-guarded beyond K). Shift-trick: thread anchors x at f4 (ogrp*16+ks);
// W read at halo-relative slot 16+ks-4jj.
// R8 vs R4 (best, 123.5): (a) KSPLIT back to 8 (R7's 16 doubled the
// per-block reduction epilogue for zero occupancy gain: k_h1 20.5->24.5);
// (b) division-free staging: wc[16][80] = halo[0,16)+main[16,80) staged via
// idx>>6/&63 (+256-slot halo pass t>>4/&15); xs[16][128] via idx>>7/&127
// (f4<112 used). Replaces ~6 magic-mul divisions/thread/chunk with shifts.
__global__ __launch_bounds__(512, 4) void k_h1(const float* __restrict__ x,
                                               const float* __restrict__ W1,
                                               float* __restrict__ h1p,
                                               float* __restrict__ gacc) {
  __shared__ float4 xs[16 * 128];  // 32 KB; row stride 128 f4
  __shared__ float4 wc[16 * 80];   // 20 KB; row stride 80 f4

  const int tile = (int)blockIdx.x >> 3;  // 0..63
  const int split = (int)blockIdx.x & 7;  // 0..7
  const int o0 = tile * 16;
  const int q0 = split * KQ;
  const int t = (int)threadIdx.x;
  const int bgrp = t >> 8;        // 0..1
  const int ogrp = (t >> 6) & 3;  // 0..3
  const int ks = t & 63;          // 0..63

  const float4 z4 = make_float4(0.f, 0.f, 0.f, 0.f);

  float acc[4][8];
#pragma unroll
  for (int j = 0; j < 4; ++j)
#pragma unroll
    for (int i = 0; i < 8; ++i) acc[j][i] = 0.f;

  // staging decompositions (loop-invariant, shifts only)
  const int wr0 = t >> 6, wf0 = t & 63;          // W main slot t
  const int wr1 = (t + 512) >> 6, wf1 = t & 63;  // W main slot t+512
  const int hr = t >> 4, hf = t & 15;            // W halo slot (t<256)

  const int nc = (split == KSPLIT - 1) ? 5 : 4;  // split 7 covers the K hole
  for (int c = 0; c < nc; ++c) {
    const int qc = q0 + c * KC;  // absolute W-column base of this chunk
    if (c > 0) __syncthreads();  // previous chunk's LDS reads complete

    // ---- stage W: main [qc, qc+256) at slots 16+f4; halo [qc-64, qc) at 0..15
    {
      float4 wm0 = z4, wm1 = z4, wh = z4;
      const int qa = qc + 4 * wf0;
      if ((o0 + wr0) < O1 && qa <= K_ - 4)
        wm0 = *(const float4*)(W1 + (o0 + wr0) * K_ + qa);
      if ((o0 + wr1) < O1 && qa <= K_ - 4)  // wf1 == wf0
        wm1 = *(const float4*)(W1 + (o0 + wr1) * K_ + qa);
      const int qh = qc - 64 + 4 * hf;
      if (t < 256 && (o0 + hr) < O1 && qh >= 0)
        wh = *(const float4*)(W1 + (o0 + hr) * K_ + qh);
      wc[wr0 * 80 + 16 + wf0] = wm0;
      wc[wr1 * 80 + 16 + wf1] = wm1;
      if (t < 256) wc[hr * 80 + hf] = wh;
    }
    // ---- stage x: rows of 112 f4 in 128-stride space
    {
      float4 tx[4];
#pragma unroll
      for (int k = 0; k < 4; ++k) {
        const int idx = t + k * 512;
        const int row = idx >> 7, f4 = idx & 127;
        float4 v = z4;
        const int p = o0 * 16 + qc + 4 * f4;
        if (f4 < 112 && p <= LC - 4) v = *(const float4*)(x + row * LC + p);
        tx[k] = v;
      }
#pragma unroll
      for (int k = 0; k < 4; ++k) {
        const int idx = t + k * 512;
        const int row = idx >> 7, f4 = idx & 127;
        if (f4 < 112) xs[row * 128 + f4] = tx[k];
      }
    }
    __syncthreads();

    // ---- compute chunk c from LDS (consecutive-lane b128 reads, no conflict)
    float4 wvv[4];
#pragma unroll
    for (int jj = 0; jj < 4; ++jj)
      wvv[jj] = wc[(ogrp * 4 + jj) * 80 + 16 + ks - 4 * jj];
    float4 xv[8];
#pragma unroll
    for (int bi = 0; bi < 8; ++bi)
      xv[bi] = xs[(bgrp * 8 + bi) * 128 + ogrp * 16 + ks];
#pragma unroll
    for (int jj = 0; jj < 4; ++jj)
#pragma unroll
      for (int bi = 0; bi < 8; ++bi) {
        acc[jj][bi] = fmaf(xv[bi].x, wvv[jj].x, acc[jj][bi]);
        acc[jj][bi] = fmaf(xv[bi].y, wvv[jj].y, acc[jj][bi]);
        acc[jj][bi] = fmaf(xv[bi].z, wvv[jj].z, acc[jj][bi]);
        acc[jj][bi] = fmaf(xv[bi].w, wvv[jj].w, acc[jj][bi]);
      }
  }

  // ---- reduce over ks (64 partials per output), 4 rounds, stride-9 pad.
  // write banks: (9*lane + i) % 32 -> 2-way (free); read banks:
  // (8*seg + bi) % 32 -> 2-way (free).
  float* redf = (float*)xs;  // 512*9 = 4608 floats <= 8192 available
  const int cls = bgrp * 4 + ogrp;  // == wave id 0..7
#pragma unroll
  for (int r = 0; r < 4; ++r) {
    __syncthreads();
#pragma unroll
    for (int i = 0; i < 8; ++i) redf[(cls * 64 + ks) * 9 + i] = acc[r][i];
    __syncthreads();
    const int out = t >> 3;  // 0..63
    const int seg = t & 7;
    const int rcls = out >> 3, bi = out & 7;
    float v = 0.f;
#pragma unroll
    for (int j = 0; j < 8; ++j)
      v += redf[(rcls * 64 + seg * 8 + j) * 9 + bi];
    v += __shfl_xor(v, 1, 64);
    v += __shfl_xor(v, 2, 64);
    v += __shfl_xor(v, 4, 64);
    if (seg == 0) {
      const int b = (rcls >> 2) * 8 + bi;
      const int o = o0 + (rcls & 3) * 4 + r;
      if (o < O1) h1p[(split * B_ + b) * O1 + o] = v;
    }
  }
  // zero lin/sig accumulators for stage 2 (stream order guarantees visibility)
  if (blockIdx.x == 0 && t < 32) gacc[t] = 0.f;
}

// ---------------- Stage 2: h2 -> partial lin/sig ----------------
__global__ __launch_bounds__(256) void k_h2(const float* __restrict__ h1p,
                                            const float* __restrict__ b1,
                                            const float* __restrict__ W2,
                                            const float* __restrict__ b2,
                                            const float* __restrict__ Wl,
                                            const float* __restrict__ Wsg,
                                            float* __restrict__ gacc) {
  const int bid = (int)blockIdx.x;
  const int b = bid >> 3;
  const int tile = bid & 7;
  const int base = tile * 64;
  const int t = (int)threadIdx.x;
  const int wave = t >> 6;
  const int lane = t & 63;

  __shared__ float hw[575];  // ELU(h1) window [base, base+575)
  for (int i = t; i < 575; i += 256) {
    const int o = base + i;
    float v = b1[o];
#pragma unroll
    for (int s = 0; s < KSPLIT; ++s) v += h1p[(s * B_ + b) * O1 + o];
    hw[i] = v > 0.f ? v : expm1f(v);  // ELU alpha=1
  }
  __syncthreads();

  float lin_acc = 0.f, sig_acc = 0.f;
  for (int i = wave; i < 64; i += 4) {
    const int o2 = base + i;
    const float4 wa = *(const float4*)(W2 + o2 * 512 + lane * 4);
    const float4 wb = *(const float4*)(W2 + o2 * 512 + 256 + lane * 4);
    const int sa = i + lane * 4;
    float a = 0.f;
    a = fmaf(hw[sa + 0], wa.x, a);
    a = fmaf(hw[sa + 1], wa.y, a);
    a = fmaf(hw[sa + 2], wa.z, a);
    a = fmaf(hw[sa + 3], wa.w, a);
    a = fmaf(hw[sa + 256], wb.x, a);
    a = fmaf(hw[sa + 257], wb.y, a);
    a = fmaf(hw[sa + 258], wb.z, a);
    a = fmaf(hw[sa + 259], wb.w, a);
#pragma unroll
    for (int off = 32; off >= 1; off >>= 1) a += __shfl_xor(a, off, 64);
    const float h2 = a + b2[o2];
    lin_acc = fmaf(h2, Wl[o2], lin_acc);
    sig_acc = fmaf(h2, Wsg[o2], sig_acc);
  }

  __shared__ float lred[4], sred[4];
  if (lane == 0) { lred[wave] = lin_acc; sred[wave] = sig_acc; }
  __syncthreads();
  if (t == 0) {
    atomicAdd(&gacc[b], lred[0] + lred[1] + lred[2] + lred[3]);
    atomicAdd(&gacc[16 + b], sred[0] + sred[1] + sred[2] + sred[3]);
  }
}

// ---------------- Stage 3: residual + batchnorm epilogue ----------------
__global__ __launch_bounds__(256) void k_out(const float* __restrict__ x,
                                             const float* __restrict__ gacc,
                                             const float* __restrict__ bl,
                                             const float* __restrict__ bs,
                                             const float* __restrict__ gamma,
                                             const float* __restrict__ beta,
                                             const float* __restrict__ mmean,
                                             const float* __restrict__ mvar,
                                             float* __restrict__ out) {
  const int f4 = blockIdx.x * 256 + (int)threadIdx.x;
  if (f4 >= B_ * OUTL * 4) return;
  const int b = f4 / (OUTL * 4);
  const int q = f4 - b * (OUTL * 4);
  const int l = q >> 2;
  const int c0 = (q & 3) * 4;

  const float lin = gacc[b] + bl[0];
  const float sv = gacc[16 + b] + bs[0];
  const float g = lin * (1.f / (1.f + expf(-sv)));

  float4 xin = make_float4(0.f, 0.f, 0.f, 0.f);
  if (l < L_) xin = *(const float4*)(x + b * LC + l * 16 + c0);

  const float4 gm = *(const float4*)(gamma + c0);
  const float4 bt = *(const float4*)(beta + c0);
  const float4 mm = *(const float4*)(mmean + c0);
  const float4 mv = *(const float4*)(mvar + c0);

  float4 r;
  r.x = (xin.x + g - mm.x) * (rsqrtf(mv.x + EPS) * gm.x) + bt.x;
  r.y = (xin.y + g - mm.y) * (rsqrtf(mv.y + EPS) * gm.y) + bt.y;
  r.z = (xin.z + g - mm.z) * (rsqrtf(mv.z + EPS) * gm.z) + bt.z;
  r.w = (xin.w + g - mm.w) * (rsqrtf(mv.w + EPS) * gm.w) + bt.w;
  *(float4*)(out + f4 * 4) = r;
}

extern "C" void kernel_launch(void* const* d_in, const int* in_sizes, int n_in,
                              void* d_out, int out_size, void* d_ws, size_t ws_size,
                              hipStream_t stream) {
  const float* x    = (const float*)d_in[0];
  const float* W1   = (const float*)d_in[1];
  const float* b1   = (const float*)d_in[2];
  const float* W2   = (const float*)d_in[3];
  const float* b2   = (const float*)d_in[4];
  const float* Wl   = (const float*)d_in[5];
  const float* bl   = (const float*)d_in[6];
  const float* Wsg  = (const float*)d_in[7];
  const float* bs   = (const float*)d_in[8];
  const float* gm   = (const float*)d_in[9];
  const float* bt   = (const float*)d_in[10];
  const float* mmn  = (const float*)d_in[11];
  const float* mvr  = (const float*)d_in[12];

  float* ws   = (float*)d_ws;
  float* h1p  = ws;                // [8][16][1023] k-split partials
  float* gacc = ws + H1P_FLOATS;   // lin[16], sig[16]

  k_h1<<<64 * KSPLIT, 512, 0, stream>>>(x, W1, h1p, gacc);
  k_h2<<<128, 256, 0, stream>>>(h1p, b1, W2, b2, Wl, Wsg, gacc);
  k_out<<<(B_ * OUTL * 4 + 255) / 256, 256, 0, stream>>>(
      x, gacc, bl, bs, gm, bt, mmn, mvr, (float*)d_out);
}